// Round 6
// baseline (184.072 us; speedup 1.0000x reference)
//
#include <hip/hip_runtime.h>
#include <hip/hip_bf16.h>

// WindowAttention for MI355X (gfx950) — round 6.
// R5: attn_proj dominant (78 us, 29% HBM, 12 barriers, 4x-redundant k reads,
// vT scatter conflicts). Fix:
//  - K1 epilogue writes the V section TRANSPOSED ([d][tok], XOR-swizzled only
//    inside K1's LDS reorder; global layout is clean [d][tok]).
//  - K2 = attn_proj2: 768 thr = 12 waves = 12 heads. Per wave: 12x1KB
//    coalesced q/k/v loads, 16 QK MFMA, in-register softmax, P via per-wave
//    LDS patch, 16 PV MFMA, write 32-col ao slice. ONE barrier, then proj
//    GEMM over 12 waves. LDS 74.5 KB -> 2 blocks/CU = 24 waves/CU.

typedef _Float16 f16;
typedef f16 f16x8 __attribute__((ext_vector_type(8)));
typedef f16 f16x4 __attribute__((ext_vector_type(4)));
typedef float f32x4 __attribute__((ext_vector_type(4)));

#define MFMA_F16(a, b, c) __builtin_amdgcn_mfma_f32_16x16x32_f16((a), (b), (c), 0, 0, 0)

#define AS_G __attribute__((address_space(1)))
#define AS_L __attribute__((address_space(3)))
#define GLOAD_LDS16(gp, lp) \
  __builtin_amdgcn_global_load_lds((const AS_G void*)(gp), (AS_L void*)(lp), 16, 0, 0)
#define WAITVM_(N) asm volatile("s_waitcnt vmcnt(" #N ")" ::: "memory")
#define WAITVM(N) WAITVM_(N)

namespace {
constexpr int kC = 384;
constexpr int kNTok = 4096;
constexpr float kScale = 0.17677669529663687f;  // 1/sqrt(32)
constexpr int kWqPackChunks = 72 * 12 * 64;     // 55296 x 16B
constexpr int kWpPackChunks = 24 * 12 * 64;     // 18432 x 16B
constexpr size_t kWqPackBytes = (size_t)kWqPackChunks * 16;  // 884736
constexpr size_t kWpPackBytes = (size_t)kWpPackChunks * 16;  // 294912
constexpr size_t kQkvWsBytes = (size_t)65536 * 1152 * 2;     // 150994944
constexpr size_t kWsNeed = kWqPackBytes + kWpPackBytes + kQkvWsBytes;
constexpr int kQkvPackChunksFb = 6 * 12 * 12 * 64;  // fallback layout
}

// ===================== split path =====================

// pack Wqkv/Wproj f16 in B-fragment order: chunk=(t*12+ks), lane=g*16+l15,
// elem j = W[ks*32+g*8+j][t*16+l15]
__global__ void prep_weights_split(const float* __restrict__ Wqkv,
                                   const float* __restrict__ Wproj,
                                   f16* __restrict__ wq_pack,
                                   f16* __restrict__ wp_pack) {
  int i = blockIdx.x * 256 + threadIdx.x;
  if (i < kWqPackChunks) {
    int lane = i & 63;
    int chunk = i >> 6;
    int ks = chunk % 12;
    int t = chunk / 12;
    int l15 = lane & 15, g = lane >> 4;
    int n3 = t * 16 + l15;
    int k0 = ks * 32 + g * 8;
    f16x8 v;
    #pragma unroll
    for (int j = 0; j < 8; ++j)
      v[j] = (f16)Wqkv[(size_t)(k0 + j) * (3 * kC) + n3];
    *reinterpret_cast<f16x8*>(wq_pack + (size_t)i * 8) = v;
  } else if (i < kWqPackChunks + kWpPackChunks) {
    int p = i - kWqPackChunks;
    int lane = p & 63;
    int chunk = p >> 6;
    int ks = chunk % 12;
    int t = chunk / 12;
    int l15 = lane & 15, g = lane >> 4;
    int n = t * 16 + l15;
    int k0 = ks * 32 + g * 8;
    f16x8 v;
    #pragma unroll
    for (int j = 0; j < 8; ++j)
      v[j] = (f16)Wproj[(size_t)(k0 + j) * kC + n];
    *reinterpret_cast<f16x8*>(wp_pack + (size_t)p * 8) = v;
  }
}

// prep_x: x f32 -> f16, window-permuted AND A-fragment-packed.
__global__ void prep_x(const float* __restrict__ x, f16* __restrict__ xw) {
  int c = blockIdx.x * 256 + threadIdx.x;  // < 4096*12*64
  int lane = c & 63;
  int t = c >> 6;
  int ks = t % 12;
  int mb = t / 12;
  int l15 = lane & 15, g = lane >> 4;
  int m = mb * 16 + l15;
  int b = m >> 12;
  int win = (m >> 6) & 63;
  int tok = m & 63;
  int n = ((win >> 3) * 8 + (tok >> 3)) * 64 + (win & 7) * 8 + (tok & 7);
  const float* src = x + ((size_t)(b << 12) + n) * kC + ks * 32 + g * 8;
  float4 v0 = *reinterpret_cast<const float4*>(src);
  float4 v1 = *reinterpret_cast<const float4*>(src + 4);
  f16x8 h = {(f16)v0.x, (f16)v0.y, (f16)v0.z, (f16)v0.w,
             (f16)v1.x, (f16)v1.y, (f16)v1.z, (f16)v1.w};
  *reinterpret_cast<f16x8*>(xw + (size_t)c * 8) = h;
}

// K1: qkv = xw @ Wqkv + b. 128x128 tile, 3-buffer counted-vmcnt pipeline.
// Output packed [b*64+win][h*3+sec][...2048]: q,k as [tok][d]; v as [d][tok].
__global__ __launch_bounds__(256, 3) void qkv_gemm2(
    const f16* __restrict__ xw, const float* __restrict__ b_qkv,
    const f16* __restrict__ wq_pack, f16* __restrict__ qkv_ws) {
  __shared__ alignas(1024) char smem[49152];

  const int tid = threadIdx.x;
  const int wid = tid >> 6;
  const int lane = tid & 63;
  const int g = lane >> 4;
  const int l15 = lane & 15;
  const int wm = wid >> 1;
  const int wn = wid & 1;

  // XCD swizzle: 4608 = 8*576; n-major within XCD -> A-panel L2 reuse.
  int bid = blockIdx.x;
  int wg = (bid & 7) * 576 + (bid >> 3);
  int m_grp = wg / 9;
  int n_grp = wg - m_grp * 9;
  const int mb0 = m_grp * 8;
  const int nb0 = n_grp * 8;

  #define STAGE(KS, BUF)                                                     \
    do {                                                                     \
      const f16* ga0 = xw + (((size_t)(mb0 + wid) * 12 + (KS)) * 64 + lane) * 8;     \
      const f16* ga1 = xw + (((size_t)(mb0 + 4 + wid) * 12 + (KS)) * 64 + lane) * 8; \
      const f16* gb0 =                                                       \
          wq_pack + (((size_t)(nb0 + wid) * 12 + (KS)) * 64 + lane) * 8;     \
      const f16* gb1 =                                                       \
          wq_pack + (((size_t)(nb0 + 4 + wid) * 12 + (KS)) * 64 + lane) * 8; \
      char* la = smem + (BUF) * 16384 + wid * 1024;                          \
      char* lb = smem + (BUF) * 16384 + 8192 + wid * 1024;                   \
      GLOAD_LDS16(ga0, la);                                                  \
      GLOAD_LDS16(ga1, la + 4096);                                           \
      GLOAD_LDS16(gb0, lb);                                                  \
      GLOAD_LDS16(gb1, lb + 4096);                                           \
    } while (0)

  f32x4 acc[4][4];
  #pragma unroll
  for (int mt = 0; mt < 4; ++mt)
    #pragma unroll
    for (int nt = 0; nt < 4; ++nt) acc[mt][nt] = {0.f, 0.f, 0.f, 0.f};

  STAGE(0, 0);
  STAGE(1, 1);
  STAGE(2, 2);
  WAITVM(8);
  __builtin_amdgcn_sched_barrier(0);
  __builtin_amdgcn_s_barrier();

  #define KITER(T, ENDVM)                                                    \
    do {                                                                     \
      constexpr int buf = (T) % 3;                                           \
      f16x8 af[4], bf[4];                                                    \
      _Pragma("unroll") for (int mt = 0; mt < 4; ++mt) af[mt] =              \
          *reinterpret_cast<const f16x8*>(smem + buf * 16384 +               \
                                          (wm * 4 + mt) * 1024 + lane * 16); \
      _Pragma("unroll") for (int nt = 0; nt < 4; ++nt) bf[nt] =              \
          *reinterpret_cast<const f16x8*>(smem + buf * 16384 + 8192 +        \
                                          (wn * 4 + nt) * 1024 + lane * 16); \
      asm volatile("s_waitcnt lgkmcnt(0)" ::: "memory");                     \
      __builtin_amdgcn_sched_barrier(0);                                     \
      __builtin_amdgcn_s_barrier();                                          \
      if ((T) < 9) {                                                         \
        STAGE((T) + 3, buf);                                                 \
      }                                                                      \
      __builtin_amdgcn_s_setprio(1);                                         \
      _Pragma("unroll") for (int mt = 0; mt < 4; ++mt)                       \
          _Pragma("unroll") for (int nt = 0; nt < 4; ++nt) acc[mt][nt] =     \
          MFMA_F16(af[mt], bf[nt], acc[mt][nt]);                             \
      __builtin_amdgcn_s_setprio(0);                                         \
      WAITVM(ENDVM);                                                         \
      __builtin_amdgcn_sched_barrier(0);                                     \
      __builtin_amdgcn_s_barrier();                                          \
    } while (0)

  KITER(0, 8);
  KITER(1, 8);
  KITER(2, 8);
  KITER(3, 8);
  KITER(4, 8);
  KITER(5, 8);
  KITER(6, 8);
  KITER(7, 8);
  KITER(8, 8);
  KITER(9, 4);
  KITER(10, 0);
  KITER(11, 0);
  #undef KITER
  #undef STAGE

  // ---- epilogue: bias, LDS re-order (v transposed+swizzled), stores ----
  f16* eo = (f16*)smem;  // [win_loc(2)][hsec_loc(4)][2048]
  #pragma unroll
  for (int nt = 0; nt < 4; ++nt) {
    int col128 = wn * 64 + nt * 16 + l15;
    float bias = b_qkv[n_grp * 128 + col128];
    int hsec_loc = wn * 2 + (nt >> 1);  // wave-uniform
    int d = col128 & 31;
    int sec = (n_grp * 4 + hsec_loc) / 12;
    int base = (wm * 4 + hsec_loc) * 2048;
    #pragma unroll
    for (int mt = 0; mt < 4; ++mt) {
      #pragma unroll
      for (int j = 0; j < 4; ++j) {
        int tok = mt * 16 + g * 4 + j;
        f16 hv = (f16)(acc[mt][nt][j] + bias);
        if (sec == 2)
          eo[base + d * 64 + (tok ^ ((d & 7) << 3))] = hv;  // [d][tok] swz
        else
          eo[base + tok * 32 + d] = hv;                      // [tok][d]
      }
    }
  }
  __syncthreads();
  #pragma unroll
  for (int i = 0; i < 8; ++i) {
    int u = tid + i * 256;
    int win_loc = u >> 10;
    int cbl = (u >> 8) & 3;
    int inner = u & 255;
    int cb = n_grp * 4 + cbl;
    int h = cb % 12;
    int sec = cb / 12;
    size_t dst = ((size_t)(m_grp * 2 + win_loc) * 36 + h * 3 + sec) * 2048 +
                 (size_t)inner * 8;
    f16x8 hv;
    if (sec == 2) {
      int d = inner >> 3;
      int t0 = inner & 7;
      hv = *reinterpret_cast<const f16x8*>(
          eo + (win_loc * 4 + cbl) * 2048 + d * 64 + ((t0 * 8) ^ ((d & 7) << 3)));
    } else {
      hv = *reinterpret_cast<const f16x8*>(eo + (size_t)u * 8);
    }
    *reinterpret_cast<f16x8*>(qkv_ws + dst) = hv;
  }
}

// K2: 12 waves = 12 heads; barrier-free attention; fused proj.
__global__ __launch_bounds__(768, 2) void attn_proj2(
    const f16* __restrict__ qkv_ws, const f16* __restrict__ wp_pack,
    float* __restrict__ out) {
  // LDS: 50176 + 26112 = 76288 B -> 2 blocks/CU (24 waves/CU)
  __shared__ alignas(16) f16 ao[64][392];
  __shared__ alignas(16) f16 p_s[12][16][68];

  const int tid = threadIdx.x;
  const int wid = tid >> 6;  // 0..11 = head
  const int lane = tid & 63;
  const int g = lane >> 4;
  const int l15 = lane & 15;

  // XCD swizzle aligned with K1's m-panel locality
  int blk = (int)blockIdx.x;
  blk = (blk & 7) * 128 + (blk >> 3);
  const int b = blk >> 6;
  const int win = blk & 63;
  const int wh = win >> 3;
  const int ww = win & 7;

  const f32x4 zero4 = {0.f, 0.f, 0.f, 0.f};
  const f16* hb = qkv_ws + ((size_t)(b * 64 + win) * 36 + wid * 3) * 2048;

  // ---- load q,k,v fragments (12 x 1KB wave loads, issued together) ----
  f16x8 qf[4], kf[4], vf[2][2];
  #pragma unroll
  for (int mt = 0; mt < 4; ++mt)
    qf[mt] = *reinterpret_cast<const f16x8*>(hb + (mt * 16 + l15) * 32 + g * 8);
  #pragma unroll
  for (int nt = 0; nt < 4; ++nt)
    kf[nt] = *reinterpret_cast<const f16x8*>(hb + 2048 + (nt * 16 + l15) * 32 + g * 8);
  #pragma unroll
  for (int ntd = 0; ntd < 2; ++ntd)
    #pragma unroll
    for (int ks = 0; ks < 2; ++ks)
      vf[ntd][ks] = *reinterpret_cast<const f16x8*>(
          hb + 4096 + (ntd * 16 + l15) * 64 + ks * 32 + g * 8);

  // ---- S = q @ k^T (full 64x64 per wave) ----
  f32x4 sacc[4][4];
  #pragma unroll
  for (int mt = 0; mt < 4; ++mt)
    #pragma unroll
    for (int nt = 0; nt < 4; ++nt) sacc[mt][nt] = zero4;
  #pragma unroll
  for (int mt = 0; mt < 4; ++mt)
    #pragma unroll
    for (int nt = 0; nt < 4; ++nt)
      sacc[mt][nt] = MFMA_F16(qf[mt], kf[nt], sacc[mt][nt]);

  // ---- softmax + PV per 16-row chunk ----
  f32x4 oacc[4][2];
  #pragma unroll
  for (int mt = 0; mt < 4; ++mt) {
    oacc[mt][0] = zero4;
    oacc[mt][1] = zero4;
  }
  #pragma unroll
  for (int mt = 0; mt < 4; ++mt) {
    float pv[4][4];
    #pragma unroll
    for (int j = 0; j < 4; ++j) {
      float m = -1e30f;
      #pragma unroll
      for (int nt = 0; nt < 4; ++nt) {
        pv[nt][j] = sacc[mt][nt][j] * kScale;
        m = fmaxf(m, pv[nt][j]);
      }
      m = fmaxf(m, __shfl_xor(m, 1));
      m = fmaxf(m, __shfl_xor(m, 2));
      m = fmaxf(m, __shfl_xor(m, 4));
      m = fmaxf(m, __shfl_xor(m, 8));
      float s = 0.f;
      #pragma unroll
      for (int nt = 0; nt < 4; ++nt) {
        pv[nt][j] = __expf(pv[nt][j] - m);
        s += pv[nt][j];
      }
      s += __shfl_xor(s, 1);
      s += __shfl_xor(s, 2);
      s += __shfl_xor(s, 4);
      s += __shfl_xor(s, 8);
      float inv = 1.0f / s;
      #pragma unroll
      for (int nt = 0; nt < 4; ++nt)
        p_s[wid][g * 4 + j][nt * 16 + l15] = (f16)(pv[nt][j] * inv);
    }
    // PV for this chunk (in-wave LDS dependency, no barrier)
    #pragma unroll
    for (int ks = 0; ks < 2; ++ks) {
      f16x8 pa =
          *reinterpret_cast<const f16x8*>(&p_s[wid][l15][ks * 32 + g * 8]);
      #pragma unroll
      for (int ntd = 0; ntd < 2; ++ntd)
        oacc[mt][ntd] = MFMA_F16(pa, vf[ntd][ks], oacc[mt][ntd]);
    }
    #pragma unroll
    for (int ntd = 0; ntd < 2; ++ntd)
      #pragma unroll
      for (int j = 0; j < 4; ++j)
        ao[mt * 16 + g * 4 + j][wid * 32 + ntd * 16 + l15] =
            (f16)oacc[mt][ntd][j];
  }
  __syncthreads();  // the ONLY block barrier: ao complete

  // ---- proj: out_win(64x384) = ao @ Wp; wave: all 4 m-tiles, 2 n-tiles ----
  f32x4 pacc[4][2];
  #pragma unroll
  for (int mt = 0; mt < 4; ++mt) {
    pacc[mt][0] = zero4;
    pacc[mt][1] = zero4;
  }
  const f16* pptr[2];
  #pragma unroll
  for (int nt = 0; nt < 2; ++nt) {
    int t = wid * 2 + nt;
    pptr[nt] = wp_pack + ((size_t)(t * 12) * 64 + lane) * 8;
  }
  f16x8 pbf[2][2];
  #pragma unroll
  for (int nt = 0; nt < 2; ++nt)
    pbf[0][nt] = *reinterpret_cast<const f16x8*>(pptr[nt]);

  #pragma unroll
  for (int ks = 0; ks < 12; ++ks) {
    const int cur = ks & 1;
    if (ks < 11) {
      #pragma unroll
      for (int nt = 0; nt < 2; ++nt)
        pbf[cur ^ 1][nt] =
            *reinterpret_cast<const f16x8*>(pptr[nt] + (ks + 1) * 512);
    }
    f16x8 paf[4];
    #pragma unroll
    for (int mt = 0; mt < 4; ++mt)
      paf[mt] = *reinterpret_cast<const f16x8*>(
          &ao[mt * 16 + l15][ks * 32 + g * 8]);
    #pragma unroll
    for (int mt = 0; mt < 4; ++mt)
      #pragma unroll
      for (int nt = 0; nt < 2; ++nt)
        pacc[mt][nt] = MFMA_F16(paf[mt], pbf[cur][nt], pacc[mt][nt]);
  }

  const size_t outbase = (size_t)b * kNTok * kC;
  #pragma unroll
  for (int mt = 0; mt < 4; ++mt) {
    #pragma unroll
    for (int j = 0; j < 4; ++j) {
      int r = mt * 16 + g * 4 + j;
      int n = (wh * 8 + (r >> 3)) * 64 + ww * 8 + (r & 7);
      float* orow = out + outbase + (size_t)n * kC + wid * 32;
      #pragma unroll
      for (int nt = 0; nt < 2; ++nt) orow[nt * 16 + l15] = pacc[mt][nt][j];
    }
  }
}

// ===================== fallback path (round-3 fused kernel) =====================

__global__ void prep_weights_fb(const float* __restrict__ Wqkv,
                                const float* __restrict__ Wproj,
                                f16* __restrict__ wq_pack,
                                f16* __restrict__ wp_pack) {
  int i = blockIdx.x * 256 + threadIdx.x;
  if (i < kQkvPackChunksFb) {
    int lane = i & 63;
    int chunk = i >> 6;
    int ks = chunk % 12;
    int t = (chunk / 12) % 12;
    int hp = chunk / 144;
    int l15 = lane & 15, g = lane >> 4;
    int base = t * 16;
    int hh = base / 96;
    int cc = base - hh * 96;
    int sec = cc >> 5;
    int dbhi = cc & 31;
    int n3 = sec * kC + (2 * hp + hh) * 32 + dbhi + l15;
    int k0 = ks * 32 + g * 8;
    f16x8 v;
    #pragma unroll
    for (int j = 0; j < 8; ++j)
      v[j] = (f16)Wqkv[(size_t)(k0 + j) * (3 * kC) + n3];
    *reinterpret_cast<f16x8*>(wq_pack + (size_t)i * 8) = v;
  } else if (i < kQkvPackChunksFb + kWpPackChunks) {
    int p = i - kQkvPackChunksFb;
    int lane = p & 63;
    int chunk = p >> 6;
    int ks = chunk % 12;
    int t = chunk / 12;
    int l15 = lane & 15, g = lane >> 4;
    int n = t * 16 + l15;
    int k0 = ks * 32 + g * 8;
    f16x8 v;
    #pragma unroll
    for (int j = 0; j < 8; ++j)
      v[j] = (f16)Wproj[(size_t)(k0 + j) * kC + n];
    *reinterpret_cast<f16x8*>(wp_pack + (size_t)p * 8) = v;
  }
}

__global__ __launch_bounds__(512, 2) void win_attn_fused_fb(
    const float* __restrict__ x, const float* __restrict__ b_qkv,
    const f16* __restrict__ wq_pack, const f16* __restrict__ wp_pack,
    float* __restrict__ out) {
  __shared__ alignas(16) f16 xs[64][392];
  __shared__ alignas(16) f16 ao[64][392];
  __shared__ alignas(16) f16 q_s[2][64][40];
  __shared__ alignas(16) f16 k_s[2][64][40];
  __shared__ alignas(16) f16 vT[2][32][72];
  __shared__ alignas(16) f16 p_s[8][16][72];

  const int tid = threadIdx.x;
  const int wid = tid >> 6;
  const int lane = tid & 63;
  const int g = lane >> 4;
  const int l15 = lane & 15;
  const int wm = wid >> 2;
  const int wn = wid & 3;

  const int blk = blockIdx.x;
  const int b = blk >> 6;
  const int win = blk & 63;
  const int wh = win >> 3;
  const int ww = win & 7;

  const f32x4 zero4 = {0.f, 0.f, 0.f, 0.f};

  {
    const float* xb = x + (size_t)b * kNTok * kC;
    #pragma unroll
    for (int it = 0; it < 12; ++it) {
      int idx = tid + it * 512;
      int r = idx / 96;
      int c4 = idx - r * 96;
      int n = (wh * 8 + (r >> 3)) * 64 + ww * 8 + (r & 7);
      float4 v = *reinterpret_cast<const float4*>(xb + (size_t)n * kC + c4 * 4);
      f16x4 hv = {(f16)v.x, (f16)v.y, (f16)v.z, (f16)v.w};
      *reinterpret_cast<f16x4*>(&xs[r][c4 * 4]) = hv;
    }
  }
  __syncthreads();

  for (int hp = 0; hp < 6; ++hp) {
    f32x4 acc[2][3];
    #pragma unroll
    for (int mt = 0; mt < 2; ++mt)
      #pragma unroll
      for (int nt = 0; nt < 3; ++nt) acc[mt][nt] = zero4;

    const f16* bptr[3];
    int secv[3], dbv[3], hhv[3];
    #pragma unroll
    for (int nt = 0; nt < 3; ++nt) {
      int t = wn * 3 + nt;
      int base = t * 16;
      int hh = base / 96;
      int cc = base - hh * 96;
      hhv[nt] = hh;
      secv[nt] = cc >> 5;
      dbv[nt] = cc & 31;
      bptr[nt] = wq_pack + ((size_t)((hp * 12 + t) * 12) * 64 + lane) * 8;
    }

    f16x8 bf[4][3];
    f16x8 af[2][2];
    #pragma unroll
    for (int p = 0; p < 3; ++p)
      #pragma unroll
      for (int nt = 0; nt < 3; ++nt)
        bf[p][nt] = *reinterpret_cast<const f16x8*>(bptr[nt] + p * 512);
    #pragma unroll
    for (int mt = 0; mt < 2; ++mt)
      af[0][mt] = *reinterpret_cast<const f16x8*>(
          &xs[wm * 32 + mt * 16 + l15][g * 8]);

    #pragma unroll
    for (int ks = 0; ks < 12; ++ks) {
      const int cur = ks & 3;
      const int ca = ks & 1;
      if (ks < 9) {
        const int nx = (ks + 3) & 3;
        #pragma unroll
        for (int nt = 0; nt < 3; ++nt)
          bf[nx][nt] =
              *reinterpret_cast<const f16x8*>(bptr[nt] + (ks + 3) * 512);
      }
      if (ks < 11) {
        #pragma unroll
        for (int mt = 0; mt < 2; ++mt)
          af[ca ^ 1][mt] = *reinterpret_cast<const f16x8*>(
              &xs[wm * 32 + mt * 16 + l15][(ks + 1) * 32 + g * 8]);
      }
      #pragma unroll
      for (int mt = 0; mt < 2; ++mt)
        #pragma unroll
        for (int nt = 0; nt < 3; ++nt)
          acc[mt][nt] = MFMA_F16(af[ca][mt], bf[cur][nt], acc[mt][nt]);
    }

    #pragma unroll
    for (int nt = 0; nt < 3; ++nt) {
      int hh = hhv[nt], sec = secv[nt];
      int col = dbv[nt] + l15;
      float bias = b_qkv[sec * kC + (2 * hp + hh) * 32 + col];
      #pragma unroll
      for (int mt = 0; mt < 2; ++mt) {
        #pragma unroll
        for (int j = 0; j < 4; ++j) {
          int r = wm * 32 + mt * 16 + g * 4 + j;
          f16 hv = (f16)(acc[mt][nt][j] + bias);
          if (sec == 0) q_s[hh][r][col] = hv;
          else if (sec == 1) k_s[hh][r][col] = hv;
          else vT[hh][col][r] = hv;
        }
      }
    }
    __syncthreads();

    f32x4 sacc[4];
    #pragma unroll
    for (int nt = 0; nt < 4; ++nt) sacc[nt] = zero4;
    f16x8 qa = *reinterpret_cast<const f16x8*>(&q_s[wm][wn * 16 + l15][g * 8]);
    #pragma unroll
    for (int nt = 0; nt < 4; ++nt) {
      f16x8 kb =
          *reinterpret_cast<const f16x8*>(&k_s[wm][nt * 16 + l15][g * 8]);
      sacc[nt] = MFMA_F16(qa, kb, sacc[nt]);
    }

    float pv[4][4];
    #pragma unroll
    for (int j = 0; j < 4; ++j) {
      float m = -1e30f;
      #pragma unroll
      for (int nt = 0; nt < 4; ++nt) {
        pv[nt][j] = sacc[nt][j] * kScale;
        m = fmaxf(m, pv[nt][j]);
      }
      m = fmaxf(m, __shfl_xor(m, 1));
      m = fmaxf(m, __shfl_xor(m, 2));
      m = fmaxf(m, __shfl_xor(m, 4));
      m = fmaxf(m, __shfl_xor(m, 8));
      float s = 0.f;
      #pragma unroll
      for (int nt = 0; nt < 4; ++nt) {
        pv[nt][j] = __expf(pv[nt][j] - m);
        s += pv[nt][j];
      }
      s += __shfl_xor(s, 1);
      s += __shfl_xor(s, 2);
      s += __shfl_xor(s, 4);
      s += __shfl_xor(s, 8);
      float inv = 1.0f / s;
      #pragma unroll
      for (int nt = 0; nt < 4; ++nt)
        p_s[wid][g * 4 + j][nt * 16 + l15] = (f16)(pv[nt][j] * inv);
    }

    f32x4 oacc[2];
    oacc[0] = zero4;
    oacc[1] = zero4;
    #pragma unroll
    for (int ks = 0; ks < 2; ++ks) {
      f16x8 pa =
          *reinterpret_cast<const f16x8*>(&p_s[wid][l15][ks * 32 + g * 8]);
      #pragma unroll
      for (int nt = 0; nt < 2; ++nt) {
        f16x8 vb = *reinterpret_cast<const f16x8*>(
            &vT[wm][nt * 16 + l15][ks * 32 + g * 8]);
        oacc[nt] = MFMA_F16(pa, vb, oacc[nt]);
      }
    }
    #pragma unroll
    for (int nt = 0; nt < 2; ++nt)
      #pragma unroll
      for (int j = 0; j < 4; ++j)
        ao[wn * 16 + g * 4 + j][(2 * hp + wm) * 32 + nt * 16 + l15] =
            (f16)oacc[nt][j];
    __syncthreads();
  }

  f32x4 pacc[2][6];
  #pragma unroll
  for (int mt = 0; mt < 2; ++mt)
    #pragma unroll
    for (int nt = 0; nt < 6; ++nt) pacc[mt][nt] = zero4;

  const f16* pptr[6];
  #pragma unroll
  for (int nt = 0; nt < 6; ++nt) {
    int t = wn * 6 + nt;
    pptr[nt] = wp_pack + ((size_t)(t * 12) * 64 + lane) * 8;
  }
  f16x8 pbf[3][6];
  f16x8 paf[2][2];
  #pragma unroll
  for (int p = 0; p < 2; ++p)
    #pragma unroll
    for (int nt = 0; nt < 6; ++nt)
      pbf[p][nt] = *reinterpret_cast<const f16x8*>(pptr[nt] + p * 512);
  #pragma unroll
  for (int mt = 0; mt < 2; ++mt)
    paf[0][mt] =
        *reinterpret_cast<const f16x8*>(&ao[wm * 32 + mt * 16 + l15][g * 8]);

  #pragma unroll
  for (int ks = 0; ks < 12; ++ks) {
    const int cur = ks % 3;
    const int ca = ks & 1;
    if (ks < 10) {
      const int nx = (ks + 2) % 3;
      #pragma unroll
      for (int nt = 0; nt < 6; ++nt)
        pbf[nx][nt] =
            *reinterpret_cast<const f16x8*>(pptr[nt] + (ks + 2) * 512);
    }
    if (ks < 11) {
      #pragma unroll
      for (int mt = 0; mt < 2; ++mt)
        paf[ca ^ 1][mt] = *reinterpret_cast<const f16x8*>(
            &ao[wm * 32 + mt * 16 + l15][(ks + 1) * 32 + g * 8]);
    }
    #pragma unroll
    for (int mt = 0; mt < 2; ++mt)
      #pragma unroll
      for (int nt = 0; nt < 6; ++nt)
        pacc[mt][nt] = MFMA_F16(paf[ca][mt], pbf[cur][nt], pacc[mt][nt]);
  }

  const size_t outbase = (size_t)b * kNTok * kC;
  #pragma unroll
  for (int mt = 0; mt < 2; ++mt) {
    #pragma unroll
    for (int j = 0; j < 4; ++j) {
      int r = wm * 32 + mt * 16 + g * 4 + j;
      int n = (wh * 8 + (r >> 3)) * 64 + ww * 8 + (r & 7);
      float* orow = out + outbase + (size_t)n * kC + wn * 96;
      #pragma unroll
      for (int nt = 0; nt < 6; ++nt) orow[nt * 16 + l15] = pacc[mt][nt][j];
    }
  }
}

// ===================== launch =====================

extern "C" void kernel_launch(void* const* d_in, const int* in_sizes, int n_in,
                              void* d_out, int out_size, void* d_ws,
                              size_t ws_size, hipStream_t stream) {
  const float* x = (const float*)d_in[0];
  const float* Wqkv = (const float*)d_in[1];
  const float* bqkv = (const float*)d_in[2];
  const float* Wproj = (const float*)d_in[3];
  float* out = (float*)d_out;

  if (ws_size >= kWsNeed) {
    f16* wq_pack = (f16*)d_ws;
    f16* wp_pack = (f16*)((char*)d_ws + kWqPackBytes);
    f16* qkv_ws = (f16*)((char*)d_ws + kWqPackBytes + kWpPackBytes);
    f16* xw = (f16*)d_out;  // 50 MB scratch inside the 100 MB output buffer

    int prep_threads = kWqPackChunks + kWpPackChunks;  // 73728
    hipLaunchKernelGGL(prep_weights_split, dim3((prep_threads + 255) / 256),
                       dim3(256), 0, stream, Wqkv, Wproj, wq_pack, wp_pack);
    hipLaunchKernelGGL(prep_x, dim3(12288), dim3(256), 0, stream, x, xw);
    hipLaunchKernelGGL(qkv_gemm2, dim3(4608), dim3(256), 0, stream, xw, bqkv,
                       wq_pack, qkv_ws);
    hipLaunchKernelGGL(attn_proj2, dim3(16 * 64), dim3(768), 0, stream, qkv_ws,
                       wp_pack, out);
  } else {
    f16* wq_pack = (f16*)d_ws;
    f16* wp_pack = (f16*)((char*)d_ws + (size_t)kQkvPackChunksFb * 16);
    int prep_threads = kQkvPackChunksFb + kWpPackChunks;
    hipLaunchKernelGGL(prep_weights_fb, dim3((prep_threads + 255) / 256),
                       dim3(256), 0, stream, Wqkv, Wproj, wq_pack, wp_pack);
    hipLaunchKernelGGL(win_attn_fused_fb, dim3(16 * 64), dim3(512), 0, stream,
                       x, bqkv, wq_pack, wp_pack, out);
  }
}